// Round 6
// baseline (170.267 us; speedup 1.0000x reference)
//
#include <hip/hip_runtime.h>

typedef unsigned int uint32;
typedef unsigned short ushort;
typedef __attribute__((ext_vector_type(8))) short short8;   // 8 bf16 = 4 VGPR
typedef __attribute__((ext_vector_type(4))) float f32x4;

#define NNODES 32768
#define NGRAPH 128
#define PNODES 256
#define SQ 32
#define NEDGE 524288
#define DIM 128
#define NHEAD 4

__device__ __forceinline__ float u2f(uint32 u){ union{uint32 i; float f;} c; c.i=u; return c.f; }
__device__ __forceinline__ uint32 f2bf(float f){
  union{float f; uint32 i;} c; c.f=f;
  return (c.i + 0x7FFFu + ((c.i>>16)&1u)) >> 16;
}
__device__ __forceinline__ uint32 pk2(float a, float b){ return f2bf(a) | (f2bf(b)<<16); }

// ---------------- zero the histogram ----------------
__global__ void k_zero(int4* __restrict__ p){
  p[blockIdx.x*256 + threadIdx.x] = int4{0,0,0,0};   // grid 32
}

// ---------------- histogram of dst ----------------
__global__ void k_hist(const int* __restrict__ dst, int* __restrict__ cnt){
  int e = blockIdx.x*256 + threadIdx.x;
  atomicAdd(&cnt[dst[e]], 1);
}

// ---------------- prefix sum + dinv ----------------
__global__ __launch_bounds__(1024) void k_scan(const int* __restrict__ cnt,
                                               int* __restrict__ start,
                                               int* __restrict__ wptr,
                                               float* __restrict__ dinv){
  __shared__ int ps[1024];
  const int t = threadIdx.x;
  const int base = t*32;
  int loc[32];
  int s = 0;
  #pragma unroll
  for (int i = 0; i < 32; ++i){
    int c = cnt[base+i];
    loc[i] = s; s += c;
    dinv[base+i] = rsqrtf((float)(c + 1));
  }
  ps[t] = s;
  __syncthreads();
  #pragma unroll 1
  for (int off = 1; off < 1024; off <<= 1){
    int v = (t >= off) ? ps[t-off] : 0;
    __syncthreads();
    ps[t] += v;
    __syncthreads();
  }
  const int pre = (t == 0) ? 0 : ps[t-1];
  #pragma unroll
  for (int i = 0; i < 32; ++i){
    int v = pre + loc[i];
    start[base+i] = v;
    wptr[base+i]  = v;
  }
  if (t == 0) start[NNODES] = NEDGE;
}

// ---------------- bucket edges by dst ----------------
__global__ void k_sort(const int* __restrict__ ei, int* __restrict__ wptr,
                       int* __restrict__ ssrc){
  int e = blockIdx.x*256 + threadIdx.x;
  int s = ei[e];
  int d = ei[NEDGE + e];
  int pos = atomicAdd(&wptr[d], 1);
  ssrc[pos] = s;
}

// ---------------- one-time weight transpose+convert: WT[n][k] = bf16(W[k][n]) ----------------
__global__ __launch_bounds__(256) void k_prep(const float* __restrict__ Wk,
    const float* __restrict__ Wv, const float* __restrict__ Wq,
    ushort* __restrict__ WTk, ushort* __restrict__ WTv, ushort* __restrict__ WTq){
  __shared__ __align__(16) float Ws2[128*132];
  const float* W = (blockIdx.x==0) ? Wk : (blockIdx.x==1) ? Wv : Wq;
  ushort* WT     = (blockIdx.x==0) ? WTk : (blockIdx.x==1) ? WTv : WTq;
  const int t = threadIdx.x;
  for (int idx = t; idx < 4096; idx += 256){
    int k = idx >> 5, c4 = idx & 31;
    *(float4*)&Ws2[k*132 + c4*4] = *(const float4*)&W[k*128 + c4*4];
  }
  __syncthreads();
  for (int idx = t; idx < 2048; idx += 256){
    int n = idx & 127, c8 = idx >> 7;
    uint4 p;
    p.x = pk2(Ws2[(c8*8+0)*132 + n], Ws2[(c8*8+1)*132 + n]);
    p.y = pk2(Ws2[(c8*8+2)*132 + n], Ws2[(c8*8+3)*132 + n]);
    p.z = pk2(Ws2[(c8*8+4)*132 + n], Ws2[(c8*8+5)*132 + n]);
    p.w = pk2(Ws2[(c8*8+6)*132 + n], Ws2[(c8*8+7)*132 + n]);
    *(uint4*)&WT[n*128 + c8*8] = p;
  }
}

// ---------------- fused aggregation + K/V GEMM per half-graph ----------------
// Builds normalized dense adjacency A (bf16, CAS-packed) in LDS, xa = A @ x via
// MFMA, then K = xa@Wk + bk, V = xa@Wv + bv via MFMA. 2 blocks/graph, 512 thr.
#define APITCH 132   // u32 per A row (= 264 ushort)
__global__ __launch_bounds__(512) void k_aggkv(
    const int* __restrict__ start, const int* __restrict__ ssrc,
    const float* __restrict__ x, const float* __restrict__ dinv,
    const ushort* __restrict__ WTk, const float* __restrict__ bk, float* __restrict__ Kf,
    const ushort* __restrict__ WTv, const float* __restrict__ bv, float* __restrict__ Vf)
{
  __shared__ __align__(16) char lds[138240];
  uint32* A    = (uint32*)lds;             // [128][132] u32 = bf16 pairs [dst][src]
  ushort* Au   = (ushort*)lds;             // [128][264] bf16 view
  ushort* xT   = (ushort*)(lds + 67584);   // [128 feat][264 src] bf16
  ushort* xa_s = (ushort*)(lds + 67584);   // [128][136] bf16 (after agg; overlays xT)
  ushort* wtA  = (ushort*)(lds + 102400);  // [128][136] bf16 (Wk^T)
  ushort* wtB  = (ushort*)(lds + 0);       // [128][136] bf16 (Wv^T; overlays A)
  float*  dvs  = (float*)(lds + 137216);   // [256]
  const int t = threadIdx.x;
  const int g = blockIdx.x >> 1, half = blockIdx.x & 1;
  const int base = g*PNODES;
  const int rbase = half*128;

  // P0: dinv slice + zero A
  if (t < 256) dvs[t] = dinv[base + t];
  for (int i = t; i < 128*APITCH; i += 512) A[i] = 0;
  __syncthreads();
  // P1: diagonal (self-loop dn^2) + stage x^T bf16
  if (t < 128){
    float dn = dvs[rbase + t];
    int src = rbase + t;
    uint32 nb = f2bf(dn*dn);
    A[t*APITCH + (src>>1)] = (src & 1) ? (nb<<16) : nb;
  }
  for (int idx = t; idx < PNODES*DIM; idx += 512){
    int s = idx >> 7, f = idx & 127;
    xT[f*264 + s] = (ushort)f2bf(x[(base+s)*DIM + f]);
  }
  __syncthreads();
  // P2: edge scatter into A via CAS (handles duplicates + self-edges)
  {
    const int r = t >> 2, sub = t & 3;
    const int n = base + rbase + r;
    const float dn = dvs[rbase + r];
    const int s1 = start[n+1];
    for (int e = start[n] + sub; e < s1; e += 4){
      int src = ssrc[e] - base;
      float coef = dn * dvs[src];
      uint32* cell = &A[r*APITCH + (src>>1)];
      const bool hi = src & 1;
      uint32 old = *cell, assumed;
      do {
        assumed = old;
        uint32 hb = hi ? (old >> 16) : (old & 0xffffu);
        float cur = u2f(hb << 16);
        uint32 nb = f2bf(cur + coef);
        uint32 nw = hi ? ((old & 0xffffu) | (nb<<16)) : ((old & 0xffff0000u) | nb);
        old = atomicCAS(cell, assumed, nw);
      } while (old != assumed);
    }
  }
  __syncthreads();
  // P3: xa = A @ x  (wave w owns rows [w*16, w*16+16))
  const int lane = t & 63, w = t >> 6;
  const int r16 = lane & 15, kg = lane >> 4;
  f32x4 acc[8];
  #pragma unroll
  for (int j = 0; j < 8; ++j) acc[j] = (f32x4){0.f,0.f,0.f,0.f};
  #pragma unroll
  for (int kc = 0; kc < 8; ++kc){
    const short8 a = *(const short8*)&Au[(w*16 + r16)*264 + kc*32 + kg*8];
    #pragma unroll
    for (int ct = 0; ct < 8; ++ct){
      const short8 b = *(const short8*)&xT[(ct*16 + r16)*264 + kc*32 + kg*8];
      acc[ct] = __builtin_amdgcn_mfma_f32_16x16x32_bf16(a, b, acc[ct], 0, 0, 0);
    }
  }
  __syncthreads();
  // P4: write xa bf16 into LDS + stage both weight matrices
  #pragma unroll
  for (int ct = 0; ct < 8; ++ct)
    #pragma unroll
    for (int q = 0; q < 4; ++q)
      xa_s[(w*16 + kg*4 + q)*136 + ct*16 + r16] = (ushort)f2bf(acc[ct][q]);
  for (int idx = t; idx < 2048; idx += 512){
    int n = idx >> 4, c8 = idx & 15;
    *(uint4*)&wtA[n*136 + c8*8] = *(const uint4*)&WTk[n*128 + c8*8];
    *(uint4*)&wtB[n*136 + c8*8] = *(const uint4*)&WTv[n*128 + c8*8];
  }
  __syncthreads();
  // P5: K = xa@Wk + bk ; V = xa@Wv + bv
  {
    f32x4 k0[8], v0[8];
    #pragma unroll
    for (int j = 0; j < 8; ++j){ k0[j] = (f32x4){0.f,0.f,0.f,0.f}; v0[j] = (f32x4){0.f,0.f,0.f,0.f}; }
    #pragma unroll
    for (int kc = 0; kc < 4; ++kc){
      const short8 a = *(const short8*)&xa_s[(w*16 + r16)*136 + kc*32 + kg*8];
      #pragma unroll
      for (int ct = 0; ct < 8; ++ct){
        const short8 b0 = *(const short8*)&wtA[(ct*16 + r16)*136 + kc*32 + kg*8];
        const short8 b1 = *(const short8*)&wtB[(ct*16 + r16)*136 + kc*32 + kg*8];
        k0[ct] = __builtin_amdgcn_mfma_f32_16x16x32_bf16(a, b0, k0[ct], 0, 0, 0);
        v0[ct] = __builtin_amdgcn_mfma_f32_16x16x32_bf16(a, b1, v0[ct], 0, 0, 0);
      }
    }
    #pragma unroll
    for (int ct = 0; ct < 8; ++ct){
      const int col = ct*16 + r16;
      const float bkc = bk[col], bvc = bv[col];
      #pragma unroll
      for (int q = 0; q < 4; ++q){
        const int row = base + rbase + w*16 + kg*4 + q;
        Kf[row*DIM + col] = k0[ct][q] + bkc;
        Vf[row*DIM + col] = v0[ct][q] + bvc;
      }
    }
  }
}

// ---------------- Q GEMM: Qp = bf16(Q) @ bf16(Wq) + bq (32 blocks) ----------------
__global__ __launch_bounds__(256) void k_gemmq(
    const float* __restrict__ Qin, const ushort* __restrict__ WTq,
    const float* __restrict__ bq, float* __restrict__ Qp)
{
  __shared__ __align__(16) ushort As[128*136];
  __shared__ __align__(16) ushort Bs[128*136];
  const int t = threadIdx.x;
  const int r0 = blockIdx.x * 128;

  for (int idx = t; idx < 2048; idx += 256){
    int n = idx >> 4, c8 = idx & 15;
    *(uint4*)&Bs[n*136 + c8*8] = *(const uint4*)&WTq[n*128 + c8*8];
  }
  for (int idx = t; idx < 2048; idx += 256){
    int r = idx >> 4, c8 = idx & 15;
    const float4 f0 = *(const float4*)&Qin[(r0+r)*128 + c8*8];
    const float4 f1 = *(const float4*)&Qin[(r0+r)*128 + c8*8 + 4];
    uint4 p; p.x = pk2(f0.x,f0.y); p.y = pk2(f0.z,f0.w);
    p.z = pk2(f1.x,f1.y); p.w = pk2(f1.z,f1.w);
    *(uint4*)&As[r*136 + c8*8] = p;
  }
  __syncthreads();

  const int lane = t & 63, w = t >> 6;
  const int r16 = lane & 15, kg = lane >> 4;

  f32x4 acc[2][8];
  #pragma unroll
  for (int i = 0; i < 2; ++i)
    #pragma unroll
    for (int j = 0; j < 8; ++j)
      acc[i][j] = (f32x4){0.f,0.f,0.f,0.f};

  #pragma unroll
  for (int kc = 0; kc < 4; ++kc){
    const short8 a0 = *(const short8*)&As[(w*32      + r16)*136 + kc*32 + kg*8];
    const short8 a1 = *(const short8*)&As[(w*32 + 16 + r16)*136 + kc*32 + kg*8];
    #pragma unroll
    for (int ct = 0; ct < 8; ++ct){
      const short8 bfr = *(const short8*)&Bs[(ct*16 + r16)*136 + kc*32 + kg*8];
      acc[0][ct] = __builtin_amdgcn_mfma_f32_16x16x32_bf16(a0, bfr, acc[0][ct], 0, 0, 0);
      acc[1][ct] = __builtin_amdgcn_mfma_f32_16x16x32_bf16(a1, bfr, acc[1][ct], 0, 0, 0);
    }
  }

  #pragma unroll
  for (int ct = 0; ct < 8; ++ct){
    const float bc = bq[ct*16 + r16];
    #pragma unroll
    for (int rt = 0; rt < 2; ++rt){
      const int row = r0 + w*32 + rt*16 + kg*4;
      #pragma unroll
      for (int q = 0; q < 4; ++q)
        Qp[(row+q)*128 + ct*16 + r16] = acc[rt][ct][q] + bc;
    }
  }
}

// ---------------- fused attention + epilogue ----------------
// 4 blocks/graph (8 queries each), 256 thr. Heads looped; V^T staged bf16 for
// ds_read_b128 PV; then LN0 -> +relu(.@Wo+bo) -> LN1 on the 8 rows in-block.
__global__ __launch_bounds__(256) void k_attnepi(
    const float* __restrict__ Qp, const float* __restrict__ Kf,
    const float* __restrict__ Vf, const float* __restrict__ Wo,
    const float* __restrict__ bo, const float* __restrict__ g0,
    const float* __restrict__ b0, const float* __restrict__ g1,
    const float* __restrict__ b1, float* __restrict__ out)
{
  __shared__ __align__(16) ushort VsT[32*264];   // [d][p] bf16, 16896 B
  __shared__ __align__(16) float Pr[8*264];      // scores, 8448 B
  __shared__ __align__(16) float Ob[8*132];      // attn out rows, 4224 B
  __shared__ float rbuf[4][132];
  const int t = threadIdx.x;
  const int b = blockIdx.x >> 2, qq = blockIdx.x & 3;
  const int qr0 = b*SQ + qq*8;                    // first query row (global)
  const float* qb0 = Qp + qr0*DIM;

  #pragma unroll 1
  for (int h = 0; h < 4; ++h){
    if (h) __syncthreads();                       // prev PV done before re-stage
    // stage V^T (thread t = key p), load K row into regs
    {
      const float* vp = Vf + (b*256 + t)*DIM + h*32;
      #pragma unroll
      for (int dq = 0; dq < 8; ++dq){
        const float4 v = *(const float4*)&vp[dq*4];
        VsT[(dq*4+0)*264 + t] = (ushort)f2bf(v.x);
        VsT[(dq*4+1)*264 + t] = (ushort)f2bf(v.y);
        VsT[(dq*4+2)*264 + t] = (ushort)f2bf(v.z);
        VsT[(dq*4+3)*264 + t] = (ushort)f2bf(v.w);
      }
    }
    float kreg[32];
    {
      const float* kp = Kf + (b*256 + t)*DIM + h*32;
      #pragma unroll
      for (int q = 0; q < 8; ++q){
        const float4 v = *(const float4*)&kp[q*4];
        kreg[4*q] = v.x; kreg[4*q+1] = v.y; kreg[4*q+2] = v.z; kreg[4*q+3] = v.w;
      }
    }
    // scores: thread t = key, 8 queries (Q reads wave-uniform -> scalar)
    const float* qb = qb0 + h*32;
    #pragma unroll
    for (int s = 0; s < 8; ++s){
      float a = 0.f;
      #pragma unroll
      for (int d = 0; d < 32; ++d)
        a = fmaf(qb[s*128 + d], kreg[d], a);
      Pr[s*264 + t] = a * 0.08838834764831845f;
    }
    __syncthreads();
    // softmax: 32 threads per query row
    {
      const int row = t >> 5, j = t & 31;
      float vals[8];
      float m = -1e30f;
      #pragma unroll
      for (int u = 0; u < 8; ++u){
        vals[u] = Pr[row*264 + j + 32*u];
        m = fmaxf(m, vals[u]);
      }
      m = fmaxf(m, __shfl_xor(m, 1));
      m = fmaxf(m, __shfl_xor(m, 2));
      m = fmaxf(m, __shfl_xor(m, 4));
      m = fmaxf(m, __shfl_xor(m, 8));
      m = fmaxf(m, __shfl_xor(m, 16));
      float sum = 0.f;
      #pragma unroll
      for (int u = 0; u < 8; ++u){
        vals[u] = __expf(vals[u] - m);
        sum += vals[u];
      }
      sum += __shfl_xor(sum, 1);
      sum += __shfl_xor(sum, 2);
      sum += __shfl_xor(sum, 4);
      sum += __shfl_xor(sum, 8);
      sum += __shfl_xor(sum, 16);
      float inv = 1.f / sum;
      #pragma unroll
      for (int u = 0; u < 8; ++u)
        Pr[row*264 + j + 32*u] = vals[u] * inv;
    }
    __syncthreads();
    // PV: thread (s = t>>5, d = t&31); Pr reads broadcast, VsT b128 along p
    {
      const int s = t >> 5, d = t & 31;
      float o = 0.f;
      #pragma unroll 4
      for (int pc = 0; pc < 32; ++pc){
        const float4 p0 = *(const float4*)&Pr[s*264 + pc*8];
        const float4 p1 = *(const float4*)&Pr[s*264 + pc*8 + 4];
        const short8 v8 = *(const short8*)&VsT[d*264 + pc*8];
        const uint32* vw = (const uint32*)&v8;
        o = fmaf(p0.x, u2f(vw[0] << 16),        o);
        o = fmaf(p0.y, u2f(vw[0] & 0xffff0000u), o);
        o = fmaf(p0.z, u2f(vw[1] << 16),        o);
        o = fmaf(p0.w, u2f(vw[1] & 0xffff0000u), o);
        o = fmaf(p1.x, u2f(vw[2] << 16),        o);
        o = fmaf(p1.y, u2f(vw[2] & 0xffff0000u), o);
        o = fmaf(p1.z, u2f(vw[3] << 16),        o);
        o = fmaf(p1.w, u2f(vw[3] & 0xffff0000u), o);
      }
      Ob[s*132 + h*32 + d] = o + qb0[s*128 + h*32 + d];
    }
  }
  __syncthreads();
  // epilogue: wave w handles rows {2w, 2w+1}
  {
    const int w = t >> 6, lane = t & 63;
    #pragma unroll 1
    for (int rr = 0; rr < 2; ++rr){
      const int row = w*2 + rr;
      float x0 = Ob[row*132 + 2*lane], x1 = Ob[row*132 + 2*lane + 1];
      float s = x0 + x1;
      s += __shfl_xor(s,1); s += __shfl_xor(s,2); s += __shfl_xor(s,4);
      s += __shfl_xor(s,8); s += __shfl_xor(s,16); s += __shfl_xor(s,32);
      float mu = s * 0.0078125f;
      float d0 = x0 - mu, d1 = x1 - mu;
      float vv = d0*d0 + d1*d1;
      vv += __shfl_xor(vv,1); vv += __shfl_xor(vv,2); vv += __shfl_xor(vv,4);
      vv += __shfl_xor(vv,8); vv += __shfl_xor(vv,16); vv += __shfl_xor(vv,32);
      float rs = rsqrtf(vv*0.0078125f + 1e-5f);
      const float2 gv = *(const float2*)&g0[2*lane];
      const float2 bv = *(const float2*)&b0[2*lane];
      float y0 = d0*rs*gv.x + bv.x;
      float y1 = d1*rs*gv.y + bv.y;
      rbuf[w][2*lane] = y0; rbuf[w][2*lane+1] = y1;
      // wave-local staging: lanes of this wave only -> no block barrier needed,
      // but LDS write->read within wave needs ordering; s_waitcnt auto-inserted.
      __builtin_amdgcn_wave_barrier();
      const float2 bov = *(const float2*)&bo[2*lane];
      float a0 = bov.x, a1 = bov.y;
      #pragma unroll 4
      for (int k = 0; k < 128; ++k){
        float yk = rbuf[w][k];
        const float2 wv = *(const float2*)&Wo[k*128 + 2*lane];
        a0 = fmaf(yk, wv.x, a0);
        a1 = fmaf(yk, wv.y, a1);
      }
      float z0 = y0 + fmaxf(a0, 0.f);
      float z1 = y1 + fmaxf(a1, 0.f);
      s = z0 + z1;
      s += __shfl_xor(s,1); s += __shfl_xor(s,2); s += __shfl_xor(s,4);
      s += __shfl_xor(s,8); s += __shfl_xor(s,16); s += __shfl_xor(s,32);
      mu = s * 0.0078125f;
      d0 = z0 - mu; d1 = z1 - mu;
      vv = d0*d0 + d1*d1;
      vv += __shfl_xor(vv,1); vv += __shfl_xor(vv,2); vv += __shfl_xor(vv,4);
      vv += __shfl_xor(vv,8); vv += __shfl_xor(vv,16); vv += __shfl_xor(vv,32);
      rs = rsqrtf(vv*0.0078125f + 1e-5f);
      const float2 g1v = *(const float2*)&g1[2*lane];
      const float2 b1v = *(const float2*)&b1[2*lane];
      float o0 = d0*rs*g1v.x + b1v.x;
      float o1 = d1*rs*g1v.y + b1v.y;
      float2 o; o.x = o0; o.y = o1;
      *(float2*)&out[(qr0+row)*128 + 2*lane] = o;
    }
  }
}

extern "C" void kernel_launch(void* const* d_in, const int* in_sizes, int n_in,
                              void* d_out, int out_size, void* d_ws, size_t ws_size,
                              hipStream_t stream){
  const float* Q   = (const float*)d_in[0];
  const float* x   = (const float*)d_in[1];
  const int*   ei  = (const int*)d_in[2];
  const float* Wq  = (const float*)d_in[4];
  const float* bq  = (const float*)d_in[5];
  const float* Wk  = (const float*)d_in[6];
  const float* bk  = (const float*)d_in[7];
  const float* Wv  = (const float*)d_in[8];
  const float* bv  = (const float*)d_in[9];
  const float* Wo  = (const float*)d_in[10];
  const float* bo  = (const float*)d_in[11];
  const float* g0  = (const float*)d_in[12];
  const float* b0  = (const float*)d_in[13];
  const float* g1  = (const float*)d_in[14];
  const float* b1  = (const float*)d_in[15];

  char* ws = (char*)d_ws;
  float*  Kf   = (float*)(ws);                   // 16 MB
  float*  Vf   = (float*)(ws + 16777216);        // 16 MB
  float*  Qp   = (float*)(ws + 33554432);        // 2 MB
  float*  dinv = (float*)(ws + 35651584);        // 128 KB
  int*    cnt  = (int*)(ws + 35782656);          // 128 KB
  int*    start= (int*)(ws + 35913728);          // 128 KB + 64
  int*    wptr = (int*)(ws + 36045824);          // 128 KB
  int*    ssrc = (int*)(ws + 36176896);          // 2 MB
  ushort* WTk  = (ushort*)(ws + 38273024);       // 32 KB
  ushort* WTv  = (ushort*)(ws + 38305792);       // 32 KB
  ushort* WTq  = (ushort*)(ws + 38338560);       // 32 KB

  k_zero<<<32, 256, 0, stream>>>((int4*)cnt);
  k_hist<<<NEDGE/256, 256, 0, stream>>>(ei + NEDGE, cnt);
  k_scan<<<1, 1024, 0, stream>>>(cnt, start, wptr, dinv);
  k_sort<<<NEDGE/256, 256, 0, stream>>>(ei, wptr, ssrc);
  k_prep<<<3, 256, 0, stream>>>(Wk, Wv, Wq, WTk, WTv, WTq);
  k_aggkv<<<NGRAPH*2, 512, 0, stream>>>(start, ssrc, x, dinv, WTk, bk, Kf, WTv, bv, Vf);
  k_gemmq<<<32, 256, 0, stream>>>(Q, WTq, bq, Qp);
  k_attnepi<<<NGRAPH*4, 256, 0, stream>>>(Qp, Kf, Vf, Wo, bo, g0, b0, g1, b1, (float*)d_out);
}

// Round 7
// 128.316 us; speedup vs baseline: 1.3269x; 1.3269x over previous
//
#include <hip/hip_runtime.h>

typedef unsigned int uint32;
typedef unsigned short ushort;
typedef __attribute__((ext_vector_type(8))) short short8;   // 8 bf16 = 4 VGPR
typedef __attribute__((ext_vector_type(4))) float f32x4;

#define NNODES 32768
#define NGRAPH 128
#define PNODES 256
#define SQ 32
#define NEDGE 524288
#define DIM 128
#define NHEAD 4

__device__ __forceinline__ float u2f(uint32 u){ union{uint32 i; float f;} c; c.i=u; return c.f; }
__device__ __forceinline__ uint32 f2bf(float f){
  union{float f; uint32 i;} c; c.f=f;
  return (c.i + 0x7FFFu + ((c.i>>16)&1u)) >> 16;
}
__device__ __forceinline__ uint32 pk2(float a, float b){ return f2bf(a) | (f2bf(b)<<16); }

// ---------------- zero the histogram ----------------
__global__ void k_zero(int4* __restrict__ p){
  p[blockIdx.x*256 + threadIdx.x] = int4{0,0,0,0};   // grid 32
}

// ---------------- histogram of dst ----------------
__global__ void k_hist(const int* __restrict__ dst, int* __restrict__ cnt){
  int e = blockIdx.x*256 + threadIdx.x;
  atomicAdd(&cnt[dst[e]], 1);
}

// ---------------- prefix sum + dinv ----------------
__global__ __launch_bounds__(1024) void k_scan(const int* __restrict__ cnt,
                                               int* __restrict__ start,
                                               int* __restrict__ wptr,
                                               float* __restrict__ dinv){
  __shared__ int ps[1024];
  const int t = threadIdx.x;
  const int base = t*32;
  int loc[32];
  int s = 0;
  #pragma unroll
  for (int i = 0; i < 32; ++i){
    int c = cnt[base+i];
    loc[i] = s; s += c;
    dinv[base+i] = rsqrtf((float)(c + 1));
  }
  ps[t] = s;
  __syncthreads();
  #pragma unroll 1
  for (int off = 1; off < 1024; off <<= 1){
    int v = (t >= off) ? ps[t-off] : 0;
    __syncthreads();
    ps[t] += v;
    __syncthreads();
  }
  const int pre = (t == 0) ? 0 : ps[t-1];
  #pragma unroll
  for (int i = 0; i < 32; ++i){
    int v = pre + loc[i];
    start[base+i] = v;
    wptr[base+i]  = v;
  }
  if (t == 0) start[NNODES] = NEDGE;
}

// ---------------- bucket edges by dst ----------------
__global__ void k_sort(const int* __restrict__ ei, int* __restrict__ wptr,
                       int* __restrict__ ssrc){
  int e = blockIdx.x*256 + threadIdx.x;
  int s = ei[e];
  int d = ei[NEDGE + e];
  int pos = atomicAdd(&wptr[d], 1);
  ssrc[pos] = s;
}

// ---------------- one-time weight transpose+convert (4 matrices) ----------------
__global__ __launch_bounds__(256) void k_prep(const float* __restrict__ Wk,
    const float* __restrict__ Wv, const float* __restrict__ Wq, const float* __restrict__ Wo,
    ushort* __restrict__ WTk, ushort* __restrict__ WTv, ushort* __restrict__ WTq,
    ushort* __restrict__ WTo){
  __shared__ __align__(16) float Ws2[128*132];
  const float* W = (blockIdx.x==0) ? Wk : (blockIdx.x==1) ? Wv : (blockIdx.x==2) ? Wq : Wo;
  ushort* WT     = (blockIdx.x==0) ? WTk : (blockIdx.x==1) ? WTv : (blockIdx.x==2) ? WTq : WTo;
  const int t = threadIdx.x;
  for (int idx = t; idx < 4096; idx += 256){
    int k = idx >> 5, c4 = idx & 31;
    *(float4*)&Ws2[k*132 + c4*4] = *(const float4*)&W[k*128 + c4*4];
  }
  __syncthreads();
  for (int idx = t; idx < 2048; idx += 256){
    int n = idx & 127, c8 = idx >> 7;
    uint4 p;
    p.x = pk2(Ws2[(c8*8+0)*132 + n], Ws2[(c8*8+1)*132 + n]);
    p.y = pk2(Ws2[(c8*8+2)*132 + n], Ws2[(c8*8+3)*132 + n]);
    p.z = pk2(Ws2[(c8*8+4)*132 + n], Ws2[(c8*8+5)*132 + n]);
    p.w = pk2(Ws2[(c8*8+6)*132 + n], Ws2[(c8*8+7)*132 + n]);
    *(uint4*)&WT[n*128 + c8*8] = p;
  }
}

// ---------------- fused aggregation + K/V GEMM per half-graph (bf16 out) ----------------
#define APITCH 132   // u32 per A row (= 264 ushort)
__global__ __launch_bounds__(512) void k_aggkv(
    const int* __restrict__ start, const int* __restrict__ ssrc,
    const float* __restrict__ x, const float* __restrict__ dinv,
    const ushort* __restrict__ WTk, const float* __restrict__ bk, ushort* __restrict__ Kb,
    const ushort* __restrict__ WTv, const float* __restrict__ bv, ushort* __restrict__ Vb)
{
  __shared__ __align__(16) char lds[138240];
  uint32* A    = (uint32*)lds;             // [128][132] u32 = bf16 pairs [dst][src]
  ushort* Au   = (ushort*)lds;             // bf16 view
  ushort* xT   = (ushort*)(lds + 67584);   // [128 feat][264 src] bf16
  ushort* xa_s = (ushort*)(lds + 67584);   // [128][136] bf16 (overlays xT after agg)
  ushort* wtA  = (ushort*)(lds + 102400);  // [128][136] bf16 (Wk^T)
  ushort* wtB  = (ushort*)(lds + 0);       // [128][136] bf16 (Wv^T; overlays A)
  float*  dvs  = (float*)(lds + 137216);   // [256]
  const int t = threadIdx.x;
  const int g = blockIdx.x >> 1, half = blockIdx.x & 1;
  const int base = g*PNODES;
  const int rbase = half*128;

  if (t < 256) dvs[t] = dinv[base + t];
  for (int i = t; i < 128*APITCH; i += 512) A[i] = 0;
  __syncthreads();
  if (t < 128){
    float dn = dvs[rbase + t];
    int src = rbase + t;
    uint32 nb = f2bf(dn*dn);
    A[t*APITCH + (src>>1)] = (src & 1) ? (nb<<16) : nb;
  }
  for (int idx = t; idx < PNODES*DIM; idx += 512){
    int s = idx >> 7, f = idx & 127;
    xT[f*264 + s] = (ushort)f2bf(x[(base+s)*DIM + f]);
  }
  __syncthreads();
  {
    const int r = t >> 2, sub = t & 3;
    const int n = base + rbase + r;
    const float dn = dvs[rbase + r];
    const int s1 = start[n+1];
    for (int e = start[n] + sub; e < s1; e += 4){
      int src = ssrc[e] - base;
      float coef = dn * dvs[src];
      uint32* cell = &A[r*APITCH + (src>>1)];
      const bool hi = src & 1;
      uint32 old = *cell, assumed;
      do {
        assumed = old;
        uint32 hb = hi ? (old >> 16) : (old & 0xffffu);
        float cur = u2f(hb << 16);
        uint32 nb = f2bf(cur + coef);
        uint32 nw = hi ? ((old & 0xffffu) | (nb<<16)) : ((old & 0xffff0000u) | nb);
        old = atomicCAS(cell, assumed, nw);
      } while (old != assumed);
    }
  }
  __syncthreads();
  const int lane = t & 63, w = t >> 6;
  const int r16 = lane & 15, kg = lane >> 4;
  f32x4 acc[8];
  #pragma unroll
  for (int j = 0; j < 8; ++j) acc[j] = (f32x4){0.f,0.f,0.f,0.f};
  #pragma unroll
  for (int kc = 0; kc < 8; ++kc){
    const short8 a = *(const short8*)&Au[(w*16 + r16)*264 + kc*32 + kg*8];
    #pragma unroll
    for (int ct = 0; ct < 8; ++ct){
      const short8 b = *(const short8*)&xT[(ct*16 + r16)*264 + kc*32 + kg*8];
      acc[ct] = __builtin_amdgcn_mfma_f32_16x16x32_bf16(a, b, acc[ct], 0, 0, 0);
    }
  }
  __syncthreads();
  #pragma unroll
  for (int ct = 0; ct < 8; ++ct)
    #pragma unroll
    for (int q = 0; q < 4; ++q)
      xa_s[(w*16 + kg*4 + q)*136 + ct*16 + r16] = (ushort)f2bf(acc[ct][q]);
  for (int idx = t; idx < 2048; idx += 512){
    int n = idx >> 4, c8 = idx & 15;
    *(uint4*)&wtA[n*136 + c8*8] = *(const uint4*)&WTk[n*128 + c8*8];
    *(uint4*)&wtB[n*136 + c8*8] = *(const uint4*)&WTv[n*128 + c8*8];
  }
  __syncthreads();
  {
    f32x4 k0[8], v0[8];
    #pragma unroll
    for (int j = 0; j < 8; ++j){ k0[j] = (f32x4){0.f,0.f,0.f,0.f}; v0[j] = (f32x4){0.f,0.f,0.f,0.f}; }
    #pragma unroll
    for (int kc = 0; kc < 4; ++kc){
      const short8 a = *(const short8*)&xa_s[(w*16 + r16)*136 + kc*32 + kg*8];
      #pragma unroll
      for (int ct = 0; ct < 8; ++ct){
        const short8 b0 = *(const short8*)&wtA[(ct*16 + r16)*136 + kc*32 + kg*8];
        const short8 b1 = *(const short8*)&wtB[(ct*16 + r16)*136 + kc*32 + kg*8];
        k0[ct] = __builtin_amdgcn_mfma_f32_16x16x32_bf16(a, b0, k0[ct], 0, 0, 0);
        v0[ct] = __builtin_amdgcn_mfma_f32_16x16x32_bf16(a, b1, v0[ct], 0, 0, 0);
      }
    }
    #pragma unroll
    for (int ct = 0; ct < 8; ++ct){
      const int col = ct*16 + r16;
      const float bkc = bk[col], bvc = bv[col];
      #pragma unroll
      for (int q = 0; q < 4; ++q){
        const int row = base + rbase + w*16 + kg*4 + q;
        Kb[row*DIM + col] = (ushort)f2bf(k0[ct][q] + bkc);
        Vb[row*DIM + col] = (ushort)f2bf(v0[ct][q] + bvc);
      }
    }
  }
}

// ---------------- Q GEMM: Qp(f32 + bf16) = bf16(Q)@bf16(Wq) + bq ----------------
__global__ __launch_bounds__(256) void k_gemmq(
    const float* __restrict__ Qin, const ushort* __restrict__ WTq,
    const float* __restrict__ bq, float* __restrict__ Qpf, ushort* __restrict__ Qpb)
{
  __shared__ __align__(16) ushort As[128*136];
  __shared__ __align__(16) ushort Bs[128*136];
  const int t = threadIdx.x;
  const int r0 = blockIdx.x * 128;

  for (int idx = t; idx < 2048; idx += 256){
    int n = idx >> 4, c8 = idx & 15;
    *(uint4*)&Bs[n*136 + c8*8] = *(const uint4*)&WTq[n*128 + c8*8];
  }
  for (int idx = t; idx < 2048; idx += 256){
    int r = idx >> 4, c8 = idx & 15;
    const float4 f0 = *(const float4*)&Qin[(r0+r)*128 + c8*8];
    const float4 f1 = *(const float4*)&Qin[(r0+r)*128 + c8*8 + 4];
    uint4 p; p.x = pk2(f0.x,f0.y); p.y = pk2(f0.z,f0.w);
    p.z = pk2(f1.x,f1.y); p.w = pk2(f1.z,f1.w);
    *(uint4*)&As[r*136 + c8*8] = p;
  }
  __syncthreads();

  const int lane = t & 63, w = t >> 6;
  const int r16 = lane & 15, kg = lane >> 4;

  f32x4 acc[2][8];
  #pragma unroll
  for (int i = 0; i < 2; ++i)
    #pragma unroll
    for (int j = 0; j < 8; ++j)
      acc[i][j] = (f32x4){0.f,0.f,0.f,0.f};

  #pragma unroll
  for (int kc = 0; kc < 4; ++kc){
    const short8 a0 = *(const short8*)&As[(w*32      + r16)*136 + kc*32 + kg*8];
    const short8 a1 = *(const short8*)&As[(w*32 + 16 + r16)*136 + kc*32 + kg*8];
    #pragma unroll
    for (int ct = 0; ct < 8; ++ct){
      const short8 bfr = *(const short8*)&Bs[(ct*16 + r16)*136 + kc*32 + kg*8];
      acc[0][ct] = __builtin_amdgcn_mfma_f32_16x16x32_bf16(a0, bfr, acc[0][ct], 0, 0, 0);
      acc[1][ct] = __builtin_amdgcn_mfma_f32_16x16x32_bf16(a1, bfr, acc[1][ct], 0, 0, 0);
    }
  }

  #pragma unroll
  for (int ct = 0; ct < 8; ++ct){
    const float bc = bq[ct*16 + r16];
    #pragma unroll
    for (int rt = 0; rt < 2; ++rt){
      const int row = r0 + w*32 + rt*16 + kg*4;
      #pragma unroll
      for (int q = 0; q < 4; ++q){
        float v = acc[rt][ct][q] + bc;
        Qpf[(row+q)*128 + ct*16 + r16] = v;
        Qpb[(row+q)*128 + ct*16 + r16] = (ushort)f2bf(v);
      }
    }
  }
}

// ---------------- fused MFMA attention + epilogue ----------------
// 2 blocks/graph (16 queries), 512 threads = 8 waves. All-MFMA:
// S=Q·K^T -> softmax -> O=P·V(+Qres) -> LN0 -> relu(Y·Wo+bo)+Y -> LN1 -> out
__global__ __launch_bounds__(512) void k_attnepi(
    const ushort* __restrict__ Qpb, const float* __restrict__ Qpf,
    const ushort* __restrict__ Kb, const ushort* __restrict__ Vb,
    const ushort* __restrict__ WoT, const float* __restrict__ bo,
    const float* __restrict__ g0, const float* __restrict__ b0,
    const float* __restrict__ g1, const float* __restrict__ b1,
    float* __restrict__ out)
{
  __shared__ __align__(16) char lds[103424];
  ushort* KbS = (ushort*)lds;             // [256][136] bf16 (69632 B)
  ushort* VT  = (ushort*)lds;             // [128][264] bf16 (67584 B) overlays KbS
  ushort* WoS = (ushort*)lds;             // [128][136] bf16 (34816 B) overlays after PV
  ushort* Yb  = (ushort*)(lds + 34816);   // [16][136] bf16 (4352 B) in same region
  float*  S   = (float*)(lds + 69632);    // [16][264] f32 (16896 B)
  float*  Zf  = (float*)(lds + 69632);    // [16][132] f32 overlays S after softmax
  ushort* Pb  = (ushort*)(lds + 86528);   // [16][264] bf16 (8448 B)
  float*  Yf  = (float*)(lds + 86528);    // [16][132] f32 overlays Pb after PV
  float*  Ob  = (float*)(lds + 94976);    // [16][132] f32 (8448 B)

  const int t = threadIdx.x;
  const int w = t >> 6, lane = t & 63;
  const int r16 = lane & 15, kg = lane >> 4;
  const int g = blockIdx.x >> 1, qh = blockIdx.x & 1;
  const int qr0 = g*SQ + qh*16;

  // A: stage K (bf16, straight copy) + Q fragments to regs
  for (int idx = t; idx < 4096; idx += 512){
    int r = idx >> 4, c8 = idx & 15;
    *(uint4*)&KbS[r*136 + c8*8] = *(const uint4*)&Kb[(g*256 + r)*128 + c8*8];
  }
  short8 qf[4];
  #pragma unroll
  for (int kc = 0; kc < 4; ++kc)
    qf[kc] = *(const short8*)&Qpb[(qr0 + r16)*128 + kc*32 + kg*8];
  __syncthreads();

  // B: scores S = (Q·K^T)/sqrt(128); wave w owns key tiles {2w, 2w+1}
  {
    f32x4 sa[2];
    sa[0] = (f32x4){0.f,0.f,0.f,0.f}; sa[1] = (f32x4){0.f,0.f,0.f,0.f};
    #pragma unroll
    for (int kc = 0; kc < 4; ++kc){
      #pragma unroll
      for (int nt = 0; nt < 2; ++nt){
        const short8 bf = *(const short8*)&KbS[((w*2+nt)*16 + r16)*136 + kc*32 + kg*8];
        sa[nt] = __builtin_amdgcn_mfma_f32_16x16x32_bf16(qf[kc], bf, sa[nt], 0, 0, 0);
      }
    }
    #pragma unroll
    for (int nt = 0; nt < 2; ++nt)
      #pragma unroll
      for (int q = 0; q < 4; ++q)
        S[(kg*4+q)*264 + (w*2+nt)*16 + r16] = sa[nt][q] * 0.08838834764831845f;
  }
  __syncthreads();

  // C: softmax (32 thr/row) -> Pb bf16 ; then stage V^T over dead K buffer
  {
    const int row = t >> 5, j = t & 31;
    float vals[8];
    float m = -1e30f;
    #pragma unroll
    for (int u = 0; u < 8; ++u){
      vals[u] = S[row*264 + j + 32*u];
      m = fmaxf(m, vals[u]);
    }
    m = fmaxf(m, __shfl_xor(m, 1));
    m = fmaxf(m, __shfl_xor(m, 2));
    m = fmaxf(m, __shfl_xor(m, 4));
    m = fmaxf(m, __shfl_xor(m, 8));
    m = fmaxf(m, __shfl_xor(m, 16));
    float sum = 0.f;
    #pragma unroll
    for (int u = 0; u < 8; ++u){
      vals[u] = __expf(vals[u] - m);
      sum += vals[u];
    }
    sum += __shfl_xor(sum, 1);
    sum += __shfl_xor(sum, 2);
    sum += __shfl_xor(sum, 4);
    sum += __shfl_xor(sum, 8);
    sum += __shfl_xor(sum, 16);
    float inv = 1.f / sum;
    #pragma unroll
    for (int u = 0; u < 8; ++u)
      Pb[row*264 + j + 32*u] = (ushort)f2bf(vals[u] * inv);
  }
  // V^T staging: consecutive threads take consecutive p (conflict-free b16 writes)
  for (int idx = t; idx < 4096; idx += 512){
    int p = idx & 255, c8 = idx >> 8;
    uint4 v = *(const uint4*)&Vb[(g*256 + p)*128 + c8*8];
    const ushort* u = (const ushort*)&v;
    #pragma unroll
    for (int j2 = 0; j2 < 8; ++j2)
      VT[(c8*8 + j2)*264 + p] = u[j2];
  }
  __syncthreads();

  // D: O = P·V + Q residual ; wave w owns d-tile w
  {
    f32x4 oa = (f32x4){0.f,0.f,0.f,0.f};
    #pragma unroll
    for (int kc = 0; kc < 8; ++kc){
      const short8 pa = *(const short8*)&Pb[r16*264 + kc*32 + kg*8];
      const short8 vb = *(const short8*)&VT[(w*16 + r16)*264 + kc*32 + kg*8];
      oa = __builtin_amdgcn_mfma_f32_16x16x32_bf16(pa, vb, oa, 0, 0, 0);
    }
    #pragma unroll
    for (int q = 0; q < 4; ++q){
      const int row = kg*4 + q, col = w*16 + r16;
      Ob[row*132 + col] = oa[q] + Qpf[(qr0 + row)*128 + col];
    }
  }
  __syncthreads();

  // E: LN0 -> Yf (f32) + Yb (bf16) ; stage WoT over dead K/V buffer
  #pragma unroll
  for (int rr = 0; rr < 2; ++rr){
    const int row = w*2 + rr;
    float x0 = Ob[row*132 + 2*lane], x1 = Ob[row*132 + 2*lane + 1];
    float s = x0 + x1;
    s += __shfl_xor(s,1); s += __shfl_xor(s,2); s += __shfl_xor(s,4);
    s += __shfl_xor(s,8); s += __shfl_xor(s,16); s += __shfl_xor(s,32);
    float mu = s * 0.0078125f;
    float d0 = x0 - mu, d1 = x1 - mu;
    float vv = d0*d0 + d1*d1;
    vv += __shfl_xor(vv,1); vv += __shfl_xor(vv,2); vv += __shfl_xor(vv,4);
    vv += __shfl_xor(vv,8); vv += __shfl_xor(vv,16); vv += __shfl_xor(vv,32);
    float rs = rsqrtf(vv*0.0078125f + 1e-5f);
    const float2 gv = *(const float2*)&g0[2*lane];
    const float2 bv = *(const float2*)&b0[2*lane];
    float y0 = d0*rs*gv.x + bv.x;
    float y1 = d1*rs*gv.y + bv.y;
    Yf[row*132 + 2*lane] = y0; Yf[row*132 + 2*lane + 1] = y1;
    *(uint32*)&Yb[row*136 + 2*lane] = pk2(y0, y1);
  }
  for (int idx = t; idx < 2048; idx += 512){
    int n = idx >> 4, c8 = idx & 15;
    *(uint4*)&WoS[n*136 + c8*8] = *(const uint4*)&WoT[n*128 + c8*8];
  }
  __syncthreads();

  // F: Z = Y + relu(Y·Wo + bo) via MFMA ; wave w owns out-col tile w
  {
    f32x4 fa = (f32x4){0.f,0.f,0.f,0.f};
    #pragma unroll
    for (int kc = 0; kc < 4; ++kc){
      const short8 ya = *(const short8*)&Yb[r16*136 + kc*32 + kg*8];
      const short8 wb = *(const short8*)&WoS[(w*16 + r16)*136 + kc*32 + kg*8];
      fa = __builtin_amdgcn_mfma_f32_16x16x32_bf16(ya, wb, fa, 0, 0, 0);
    }
    #pragma unroll
    for (int q = 0; q < 4; ++q){
      const int row = kg*4 + q, col = w*16 + r16;
      Zf[row*132 + col] = Yf[row*132 + col] + fmaxf(fa[q] + bo[col], 0.f);
    }
  }
  __syncthreads();

  // G: LN1 -> out
  #pragma unroll
  for (int rr = 0; rr < 2; ++rr){
    const int row = w*2 + rr;
    float z0 = Zf[row*132 + 2*lane], z1 = Zf[row*132 + 2*lane + 1];
    float s = z0 + z1;
    s += __shfl_xor(s,1); s += __shfl_xor(s,2); s += __shfl_xor(s,4);
    s += __shfl_xor(s,8); s += __shfl_xor(s,16); s += __shfl_xor(s,32);
    float mu = s * 0.0078125f;
    float d0 = z0 - mu, d1 = z1 - mu;
    float vv = d0*d0 + d1*d1;
    vv += __shfl_xor(vv,1); vv += __shfl_xor(vv,2); vv += __shfl_xor(vv,4);
    vv += __shfl_xor(vv,8); vv += __shfl_xor(vv,16); vv += __shfl_xor(vv,32);
    float rs = rsqrtf(vv*0.0078125f + 1e-5f);
    const float2 g1v = *(const float2*)&g1[2*lane];
    const float2 b1v = *(const float2*)&b1[2*lane];
    float2 o;
    o.x = d0*rs*g1v.x + b1v.x;
    o.y = d1*rs*g1v.y + b1v.y;
    *(float2*)&out[(qr0 + row)*128 + 2*lane] = o;
  }
}

extern "C" void kernel_launch(void* const* d_in, const int* in_sizes, int n_in,
                              void* d_out, int out_size, void* d_ws, size_t ws_size,
                              hipStream_t stream){
  const float* Q   = (const float*)d_in[0];
  const float* x   = (const float*)d_in[1];
  const int*   ei  = (const int*)d_in[2];
  const float* Wq  = (const float*)d_in[4];
  const float* bq  = (const float*)d_in[5];
  const float* Wk  = (const float*)d_in[6];
  const float* bk  = (const float*)d_in[7];
  const float* Wv  = (const float*)d_in[8];
  const float* bv  = (const float*)d_in[9];
  const float* Wo  = (const float*)d_in[10];
  const float* bo  = (const float*)d_in[11];
  const float* g0  = (const float*)d_in[12];
  const float* b0  = (const float*)d_in[13];
  const float* g1  = (const float*)d_in[14];
  const float* b1  = (const float*)d_in[15];

  char* ws = (char*)d_ws;
  ushort* Kb   = (ushort*)(ws);                  // 8 MB
  ushort* Vb   = (ushort*)(ws + 8388608);        // 8 MB
  float*  Qpf  = (float*)(ws + 16777216);        // 2 MB
  ushort* Qpb  = (ushort*)(ws + 18874368);       // 1 MB
  float*  dinv = (float*)(ws + 19922944);        // 128 KB
  int*    cnt  = (int*)(ws + 20054016);          // 128 KB
  int*    start= (int*)(ws + 20185088);          // 128 KB + pad
  int*    wptr = (int*)(ws + 20320256);          // 128 KB
  int*    ssrc = (int*)(ws + 20451328);          // 2 MB
  ushort* WTk  = (ushort*)(ws + 22548480);       // 32 KB
  ushort* WTv  = (ushort*)(ws + 22581248);       // 32 KB
  ushort* WTq  = (ushort*)(ws + 22614016);       // 32 KB
  ushort* WTo  = (ushort*)(ws + 22646784);       // 32 KB

  k_zero<<<32, 256, 0, stream>>>((int4*)cnt);
  k_hist<<<NEDGE/256, 256, 0, stream>>>(ei + NEDGE, cnt);
  k_scan<<<1, 1024, 0, stream>>>(cnt, start, wptr, dinv);
  k_sort<<<NEDGE/256, 256, 0, stream>>>(ei, wptr, ssrc);
  k_prep<<<4, 256, 0, stream>>>(Wk, Wv, Wq, Wo, WTk, WTv, WTq, WTo);
  k_aggkv<<<NGRAPH*2, 512, 0, stream>>>(start, ssrc, x, dinv, WTk, bk, Kb, WTv, bv, Vb);
  k_gemmq<<<32, 256, 0, stream>>>(Q, WTq, bq, Qpf, Qpb);
  k_attnepi<<<NGRAPH*2, 512, 0, stream>>>(Qpb, Qpf, Kb, Vb, WTo, bo, g0, b0, g1, b1, (float*)d_out);
}